// Round 3
// baseline (628.487 us; speedup 1.0000x reference)
//
#include <hip/hip_runtime.h>
#include <hip/hip_bf16.h>
#include <math.h>

#define LSEQ 2048
#define NB 4
#define DM 1024
#define ZD 128
#define HD 2048
#define ND 16
#define NEXTD 256
#define EMA_C 64
#define EMA_NCH 32

typedef __bf16 bf16x8 __attribute__((ext_vector_type(8)));
typedef __bf16 bf16x4 __attribute__((ext_vector_type(4)));
typedef float f32x4 __attribute__((ext_vector_type(4)));
typedef unsigned char uchar;

__device__ __forceinline__ float sigm(float x){ return 1.0f/(1.0f+expf(-x)); }
__device__ __forceinline__ float silu_(float x){ return x/(1.0f+expf(-x)); }
__device__ __forceinline__ float laplacef(float x){ return 0.5f*(1.0f+erff((x-0.70710678f)*2.5066282746f)); }

__device__ __forceinline__ void load_lds16(const __bf16* g, __bf16* l){
  __builtin_amdgcn_global_load_lds((const __attribute__((address_space(1))) void*)g,
                                   (__attribute__((address_space(3))) void*)l, 16, 0, 0);
}
__device__ __forceinline__ void load_lds16b(const uchar* g, uchar* l){
  __builtin_amdgcn_global_load_lds((const __attribute__((address_space(1))) void*)g,
                                   (__attribute__((address_space(3))) void*)l, 16, 0, 0);
}
// pack 4 f32 -> 4 fp8 e4m3 bytes (OCP on gfx950)
__device__ __forceinline__ unsigned int pk4_fp8(float a, float b, float c, float d){
  int v = __builtin_amdgcn_cvt_pk_fp8_f32(a, b, 0, false);
  v = __builtin_amdgcn_cvt_pk_fp8_f32(c, d, v, true);
  return (unsigned int)v;
}

// ---------------- all three weights fp32 -> bf16, one launch ----------------
// Wmx rows are PERMUTED to [u(1024) | r(2048) | hx(1024) | z(128)] so that the
// 256-wide GEMM tiles never straddle an epilogue-region boundary.
__global__ __launch_bounds__(256) void f2b_all(const float4* __restrict__ w0, const float4* __restrict__ w1,
                                               const float4* __restrict__ w2, bf16x4* __restrict__ o0,
                                               bf16x4* __restrict__ o1, bf16x4* __restrict__ o2){
  const int i = blockIdx.x*256 + threadIdx.x;
  const int n0 = 524288, n1 = 1081344, n2 = 524288;
  float4 v; bf16x4* dst;
  if (i < n0){ v = w0[i]; dst = &o0[i]; }
  else if (i < n0+n1){
    const int t = i - n0;
    const int row = t >> 8, c = t & 255;
    const int r_out = (row < 1024) ? row : ((row < 1152) ? (4096 + row - 1024) : (row - 128));
    v = w1[t]; dst = &o1[r_out*256 + c];
  }
  else if (i < n0+n1+n2){ const int t = i-n0-n1; v = w2[t]; dst = &o2[t]; }
  else return;
  bf16x4 o; o[0]=(__bf16)v.x; o[1]=(__bf16)v.y; o[2]=(__bf16)v.z; o[3]=(__bf16)v.w;
  *dst = o;
}

// ---------------- LayerNorm (bf16 out, l-major [l][b][d]) ----------------
__global__ __launch_bounds__(256) void ln_kernel(const float* __restrict__ x, const float* __restrict__ w,
                                                 const float* __restrict__ b, __bf16* __restrict__ xnb){
  const long row = blockIdx.x;
  const int tid = threadIdx.x;
  float4 v = ((const float4*)(x + row*DM))[tid];
  float s = v.x+v.y+v.z+v.w;
  float ss = v.x*v.x+v.y*v.y+v.z*v.z+v.w*v.w;
#pragma unroll
  for (int o=32;o>0;o>>=1){ s += __shfl_down(s,o); ss += __shfl_down(ss,o); }
  __shared__ float red[8];
  __shared__ float mv[2];
  const int wid2 = tid>>6, lane = tid&63;
  if (lane==0){ red[wid2]=s; red[4+wid2]=ss; }
  __syncthreads();
  if (tid==0){
    float ts = red[0]+red[1]+red[2]+red[3];
    float tss = red[4]+red[5]+red[6]+red[7];
    float mean = ts*(1.0f/DM);
    float var = tss*(1.0f/DM) - mean*mean;
    mv[0]=mean; mv[1]=rsqrtf(var + 1e-5f);
  }
  __syncthreads();
  const float mean=mv[0], rs=mv[1];
  float4 wv = ((const float4*)w)[tid];
  float4 bv = ((const float4*)b)[tid];
  bf16x4 ob;
  ob[0]=(__bf16)((v.x-mean)*rs*wv.x+bv.x);
  ob[1]=(__bf16)((v.y-mean)*rs*wv.y+bv.y);
  ob[2]=(__bf16)((v.z-mean)*rs*wv.z+bv.z);
  ob[3]=(__bf16)((v.w-mean)*rs*wv.w+bv.w);
  ((bf16x4*)(xnb + row*DM))[tid]=ob;
}

// ---------------- EMA parameter precompute ----------------
__global__ __launch_bounds__(256) void ema_params_k(const float* __restrict__ de, const float* __restrict__ al,
                                                    const float* __restrict__ be, const float* __restrict__ ga,
                                                    float* __restrict__ qo, float* __restrict__ wo,
                                                    float* __restrict__ qco){
  const int i = blockIdx.x*256 + threadIdx.x;
  const float p = sigm(de[i]);
  const float q = 1.0f - p*sigm(al[i]);
  qo[i] = q;
  wo[i] = p*be[i]*ga[i]*0.25f;
  qco[i] = powf(q, (float)EMA_C);
}

// ---------------- EMA pass A ----------------
__global__ __launch_bounds__(64) void ema_chunk_k(const __bf16* __restrict__ xn, const float* __restrict__ qp,
                                                  float* __restrict__ E){
  const int d = blockIdx.x*64 + threadIdx.x;
  const int j = blockIdx.y, b = blockIdx.z;
  float q[ND], s[ND];
#pragma unroll
  for (int n=0;n<ND;n++){ q[n]=qp[d*ND+n]; s[n]=0.0f; }
  const __bf16* xc = xn + (long)b*DM + d + (long)j*EMA_C*(NB*DM);
#pragma unroll
  for (int lt=0; lt<EMA_C; lt+=4){
    float xv[4];
#pragma unroll
    for (int u=0;u<4;u++) xv[u] = (float)xc[(long)(lt+u)*(NB*DM)];
#pragma unroll
    for (int u=0;u<4;u++)
#pragma unroll
      for (int n=0;n<ND;n++) s[n] = fmaf(q[n], s[n], xv[u]);
  }
  float4* Eo = (float4*)(E + (((long)b*EMA_NCH + j)*DM + d)*ND);
#pragma unroll
  for (int n=0;n<4;n++) Eo[n] = make_float4(s[4*n], s[4*n+1], s[4*n+2], s[4*n+3]);
}

// ---------------- EMA pass B ----------------
__global__ __launch_bounds__(256) void ema_scan_k(const float* __restrict__ E, const float* __restrict__ qc,
                                                  float* __restrict__ Sinit){
  const int t = blockIdx.x*256 + threadIdx.x;
  const int b = t >> 14;
  const int rem = t & 16383;
  const float q64 = qc[rem];
  float s = 0.0f;
  const long base = (long)b*EMA_NCH*16384 + rem;
  for (int j=0;j<EMA_NCH;j++){
    const long idx = base + (long)j*16384;
    Sinit[idx] = s;
    s = fmaf(q64, s, E[idx]);
  }
}

// ---------------- EMA pass C ----------------
__global__ __launch_bounds__(64) void ema_out_k(const __bf16* __restrict__ xn, const float* __restrict__ qp,
                                                const float* __restrict__ wp, const float* __restrict__ omega,
                                                const float* __restrict__ Sinit, __bf16* __restrict__ mx){
  const int d = blockIdx.x*64 + threadIdx.x;
  const int j = blockIdx.y, b = blockIdx.z;
  float q[ND], w[ND], s[ND];
  const float4* Si = (const float4*)(Sinit + (((long)b*EMA_NCH + j)*DM + d)*ND);
#pragma unroll
  for (int n=0;n<4;n++){ float4 v=Si[n]; s[4*n]=v.x; s[4*n+1]=v.y; s[4*n+2]=v.z; s[4*n+3]=v.w; }
#pragma unroll
  for (int n=0;n<ND;n++){ q[n]=qp[d*ND+n]; w[n]=wp[d*ND+n]; }
  const float om = omega[d];
  const int l0 = j*EMA_C;
  const __bf16* xc = xn + (long)b*DM + d;
#pragma unroll
  for (int lt=0; lt<EMA_C; lt+=4){
    float xv[4];
#pragma unroll
    for (int u=0;u<4;u++) xv[u] = (float)xc[(long)(l0+lt+u)*(NB*DM)];
#pragma unroll
    for (int u=0;u<4;u++){
      float a = 0.0f;
#pragma unroll
      for (int n=0;n<ND;n++){ s[n] = fmaf(q[n], s[n], xv[u]); a = fmaf(w[n], s[n], a); }
      mx[((long)(l0+lt+u)*NB + b)*DM + d] = (__bf16)silu_(a + xv[u]*om);
    }
  }
}

// ---------------- v (L*B,H) -> vT8 (B,H,L), fp8 x8 scale ----------------
__global__ __launch_bounds__(256) void transpose_v8(const __bf16* __restrict__ v, uchar* __restrict__ vT){
  __shared__ __bf16 t[64][65];
  const int b = blockIdx.z;
  const int l0 = blockIdx.x*64, h0 = blockIdx.y*64;
  const int tx = threadIdx.x & 63, ty = threadIdx.x >> 6;
  for (int i=ty;i<64;i+=4) t[i][tx] = v[((long)(l0+i)*NB + b)*HD + h0 + tx];
  __syncthreads();
  const int h = threadIdx.x >> 2;
  const int lq = (threadIdx.x & 3) * 16;
  float f[16];
#pragma unroll
  for (int e=0;e<16;e++) f[e] = 8.0f*(float)t[lq+e][h];
  uint4 ov;
  ov.x = pk4_fp8(f[0],f[1],f[2],f[3]);
  ov.y = pk4_fp8(f[4],f[5],f[6],f[7]);
  ov.z = pk4_fp8(f[8],f[9],f[10],f[11]);
  ov.w = pk4_fp8(f[12],f[13],f[14],f[15]);
  *(uint4*)&vT[((long)b*HD + h0 + h)*LSEQ + l0 + lq] = ov;
}

// ---------------- rotary extension cols [128,256) of qx/kx (b-major) ----------------
__global__ __launch_bounds__(128) void rot_fill(const float* __restrict__ ra, const float* __restrict__ rb,
                                                __bf16* __restrict__ qx, __bf16* __restrict__ kx){
  const int l = blockIdx.x, i = threadIdx.x;
  const int jf = i & 63;
  const float f = expf((float)jf * (-0.14391156831f));
  const float ang = (float)l * f;
  const float sn = sinf(ang), cs = cosf(ang);
  float qv, kv;
  if (i < 64){ qv = ra[i]*cs - ra[i+64]*sn; kv = rb[i]*cs - rb[i+64]*sn; }
  else       { qv = ra[i]*cs + ra[i-64]*sn; kv = rb[i]*cs + rb[i-64]*sn; }
  const __bf16 qb = (__bf16)qv, kb = (__bf16)kv;
#pragma unroll
  for (int b=0;b<NB;b++){
    const long o = ((long)b*LSEQ + l)*NEXTD + 128 + i;
    qx[o] = qb;
    kx[o] = kb;
  }
}

// Supertiled XCD remap: XCD k owns m-tiles [k*mpx,(k+1)*mpx) x all n-tiles,
// so per-XCD A-working-set stays L2-resident. Requires gridDim.x % 8 == 0
// (or gridDim.x>=8 pow2) and pow2 mpx; bijective by construction.
__device__ __forceinline__ void xcd_supertile(long& m0, long& n0, int tileDim){
  const int orig = blockIdx.y*gridDim.x + blockIdx.x;
  const int xcd = orig & 7, j = orig >> 3;
  const int mpx = gridDim.x >> 3;            // power of 2 in all launches
  const int sh = __builtin_ctz(mpx);
  m0 = (long)((xcd<<sh) + (j & (mpx-1))) * tileDim;
  n0 = (long)(j >> sh) * tileDim;
}

// ---------------- 256x256-tile 8-phase bf16 GEMM (T2+T3+T4+T5) ----------------
// 512 threads = 8 waves (2M x 4N), per-wave 128x64 output, BK=64, LDS 128KiB dbuf.
// m201-template-exact phase: ds-reads -> [lgkmcnt(8) if 12 reads] -> s_barrier ->
// lgkmcnt(0) -> setprio(1) -> 16 MFMA -> setprio(0) -> s_barrier. NO sched_barrier
// (r2's fences pinned the schedule: ~513 TF == m141's failure mode). Counted
// vmcnt(8) only at phases 4/8. Supertiled XCD map keeps per-XCD A L2-resident.
// MODE 0: v=silu(.+bias) -> o0. MODE 1: permuted base -> u(sigm)/r(silu)/hx(id).
template<int MODE>
__global__ __launch_bounds__(512, 2) void gemm256(
    const __bf16* __restrict__ A, const __bf16* __restrict__ Bw,
    int K, const float* __restrict__ bias,
    void* __restrict__ o0, void* __restrict__ o1, void* __restrict__ o2)
{
  __shared__ __align__(16) char smem[131072];
  __bf16* As0 = (__bf16*)smem;
  __bf16* Bs0 = (__bf16*)(smem + 32768);
  __bf16* As1 = (__bf16*)(smem + 65536);
  __bf16* Bs1 = (__bf16*)(smem + 98304);

  const int tid = threadIdx.x;
  const int l = tid & 63;
  const int w = tid >> 6;
  const int wm = w >> 2, wn = w & 3;
  const int lane15 = l & 15;
  const int qdb = l >> 4;
  const int w8 = w << 3;
  const int l3 = l >> 3;
  const int gch = (((l & 7) ^ l3) << 3);   // pre-swizzled global chunk (elements)

  long m0, n0;
  xcd_supertile(m0, n0, 256);

  const __bf16* Apt[4];
  const __bf16* Bpt[4];
#pragma unroll
  for (int i=0;i<4;i++){
    Apt[i] = A + (m0 + i*64 + w8 + l3)*(long)K + gch;
    Bpt[i] = Bw + (n0 + i*64 + w8 + l3)*(long)K + gch;
  }
  const int NT = K >> 6;

#define STG(PT, DST, K0) { _Pragma("unroll") \
  for (int i_=0;i_<4;i_++) load_lds16(PT[i_] + (K0), (DST) + ((i_*64 + w8)<<6)); }

  f32x4 acc[8][4];
#pragma unroll
  for (int i=0;i<8;i++)
#pragma unroll
    for (int j=0;j<4;j++)
#pragma unroll
      for (int r=0;r<4;r++) acc[i][j][r]=0.0f;

  bf16x8 af[4][2], bq0[2][2], bq1[2][2];
  const int wmA = wm*128, wnB = wn*64;

  // prologue: stage tiles 0 and 1
  STG(Apt, As0, 0) STG(Bpt, Bs0, 0)
  STG(Apt, As1, 64) STG(Bpt, Bs1, 64)
  asm volatile("s_waitcnt vmcnt(8)" ::: "memory");
  __builtin_amdgcn_s_barrier();

#define LD8(BUF, R, Q) (*(const bf16x8*)&BUF[((R)<<6) + ((((Q) ^ ((R)&7))<<3))])

#define MM16(MO, NO, BF) \
  _Pragma("unroll") for (int mi=0;mi<4;mi++) \
  _Pragma("unroll") for (int nj=0;nj<2;nj++){ \
    acc[(MO)+mi][(NO)+nj] = __builtin_amdgcn_mfma_f32_16x16x32_bf16(af[mi][0], BF[nj][0], acc[(MO)+mi][(NO)+nj],0,0,0); \
    acc[(MO)+mi][(NO)+nj] = __builtin_amdgcn_mfma_f32_16x16x32_bf16(af[mi][1], BF[nj][1], acc[(MO)+mi][(NO)+nj],0,0,0); }

#define TILE(AS_, BS_, T_) { \
  /* P0: read A[m-half0] (8 b128) + B[n-half0] (4 b128) */ \
  _Pragma("unroll") for (int mi=0;mi<4;mi++){ const int r_ = wmA + mi*16 + lane15; \
    af[mi][0] = LD8(AS_, r_, qdb); af[mi][1] = LD8(AS_, r_, qdb+4); } \
  _Pragma("unroll") for (int nj=0;nj<2;nj++){ const int r_ = wnB + nj*16 + lane15; \
    bq0[nj][0] = LD8(BS_, r_, qdb); bq0[nj][1] = LD8(BS_, r_, qdb+4); } \
  asm volatile("s_waitcnt lgkmcnt(8)" ::: "memory"); \
  __builtin_amdgcn_s_barrier(); \
  asm volatile("s_waitcnt lgkmcnt(0)" ::: "memory"); \
  __builtin_amdgcn_s_setprio(1); MM16(0,0,bq0) __builtin_amdgcn_s_setprio(0); \
  __builtin_amdgcn_s_barrier(); \
  /* P1: read B[n-half1] */ \
  _Pragma("unroll") for (int nj=0;nj<2;nj++){ const int r_ = wnB + 32 + nj*16 + lane15; \
    bq1[nj][0] = LD8(BS_, r_, qdb); bq1[nj][1] = LD8(BS_, r_, qdb+4); } \
  __builtin_amdgcn_s_barrier(); \
  asm volatile("s_waitcnt lgkmcnt(0)" ::: "memory"); \
  __builtin_amdgcn_s_setprio(1); MM16(0,2,bq1) __builtin_amdgcn_s_setprio(0); \
  __builtin_amdgcn_s_barrier(); \
  /* P2: read A[m-half1]; prefetch B of tile T+2 */ \
  _Pragma("unroll") for (int mi=0;mi<4;mi++){ const int r_ = wmA + 64 + mi*16 + lane15; \
    af[mi][0] = LD8(AS_, r_, qdb); af[mi][1] = LD8(AS_, r_, qdb+4); } \
  if ((T_)+2 < NT){ STG(Bpt, BS_, ((T_)+2)<<6) } \
  __builtin_amdgcn_s_barrier(); \
  asm volatile("s_waitcnt lgkmcnt(0)" ::: "memory"); \
  __builtin_amdgcn_s_setprio(1); MM16(4,2,bq1) __builtin_amdgcn_s_setprio(0); \
  __builtin_amdgcn_s_barrier(); \
  /* P3: prefetch A of tile T+2 */ \
  if ((T_)+2 < NT){ STG(Apt, AS_, ((T_)+2)<<6) } \
  __builtin_amdgcn_s_barrier(); \
  asm volatile("s_waitcnt lgkmcnt(0)" ::: "memory"); \
  __builtin_amdgcn_s_setprio(1); MM16(4,0,bq0) __builtin_amdgcn_s_setprio(0); \
  if ((T_)+2 < NT){ asm volatile("s_waitcnt vmcnt(8)" ::: "memory"); } \
  else if ((T_)+1 < NT){ asm volatile("s_waitcnt vmcnt(0)" ::: "memory"); } \
  __builtin_amdgcn_s_barrier(); \
}

  for (int t=0; t<NT; t+=2){
    TILE(As0, Bs0, t)
    TILE(As1, Bs1, t+1)
  }

#undef TILE
#undef MM16
#undef LD8
#undef STG

  // ---------------- epilogue: stage 128-col halves through LDS ----------------
  __syncthreads();
  __bf16* st = (__bf16*)smem;       // 256 x 136 bf16
  const int quad = qdb;
  const int row_t = tid >> 1, half = tid & 1;
  const long row_g = m0 + row_t;

#pragma unroll
  for (int p=0;p<2;p++){
    if ((wn>>1) == p){
#pragma unroll
      for (int qi=0;qi<8;qi++){
        const int tr0 = wmA + (qi>>2)*64 + (qi&3)*16 + quad*4;
#pragma unroll
        for (int jj=0;jj<4;jj++){
          const int tcl = (wn&1)*64 + jj*16 + lane15;
          const long colg = n0 + p*128 + tcl;
          float bb;
          if (MODE==0) bb = bias[colg];
          else bb = bias[(colg < DM) ? colg : (colg + ZD)];   // permuted layout -> orig bias idx
#pragma unroll
          for (int r=0;r<4;r++){
            float c = acc[qi][jj][r] + bb;
            if (MODE==0) c = silu_(c);
            else c = (colg < DM) ? sigm(c) : ((colg < DM+HD) ? silu_(c) : c);
            st[(tr0+r)*136 + tcl] = (__bf16)c;
          }
        }
      }
    }
    __syncthreads();
    const long nbase = n0 + p*128 + half*64;
    __bf16* dst; long ld, coff;
    if (MODE==0){ dst = (__bf16*)o0; ld = HD; coff = nbase; }
    else {
      if (nbase < DM)          { dst = (__bf16*)o0; ld = DM; coff = nbase; }          // u
      else if (nbase < DM+HD)  { dst = (__bf16*)o1; ld = HD; coff = nbase-DM; }       // r
      else                     { dst = (__bf16*)o2; ld = DM; coff = nbase-DM-HD; }    // hx
    }
#pragma unroll
    for (int k=0;k<8;k++){
      bf16x8 vv = *(const bf16x8*)&st[row_t*136 + half*64 + k*8];
      *(bf16x8*)(dst + row_g*ld + coff + k*8) = vv;
    }
    if (p==0) __syncthreads();
  }
}

// ---------------- bf16 GEMM template (16x16x32 MFMA, m97 structure) ----------------
// Kept for MODE 2 (laplace->fp8 S), MODE 4 (final fused), MODE 5 (z-strip -> qx/kx).
template<int MODE>
__global__ __launch_bounds__(256, 4) void gemm_bt(
    const __bf16* __restrict__ A, const __bf16* __restrict__ Bw,
    int K, long aBatch, long bBatch, const float* __restrict__ bias,
    void* __restrict__ o0, void* __restrict__ o1, void* __restrict__ o2, void* __restrict__ o3,
    const void* __restrict__ x0, const void* __restrict__ x1, const void* __restrict__ x2)
{
  __shared__ __align__(16) char smem_raw[34816];
  __bf16* As = (__bf16*)smem_raw;
  __bf16* Bs = (__bf16*)(smem_raw + 16384);
  const int tid = threadIdx.x;
  const int lane = tid & 63;
  const int wid = tid >> 6;
  const int bz = blockIdx.z;
  long m0, n0;
  xcd_supertile(m0, n0, 128);
  const __bf16* Ab = A + (long)bz * aBatch;
  const __bf16* Bb = Bw + (long)bz * bBatch;
  const int wm = wid & 1, wn = wid >> 1;
  const int lrow = lane >> 3;
  const int gchunk = (lane & 7) ^ lrow;

  f32x4 acc[4][4];
#pragma unroll
  for (int i=0;i<4;i++)
#pragma unroll
    for (int j=0;j<4;j++)
#pragma unroll
      for (int r=0;r<4;r++) acc[i][j][r] = 0.0f;

  for (int k0=0;k0<K;k0+=64){
    __syncthreads();
#pragma unroll
    for (int j=0;j<4;j++){
      const int g = j*4 + wid;
      const long ar = m0 + g*8 + lrow;
      load_lds16(Ab + ar*(long)K + (k0 + gchunk*8), &As[g*512]);
      const long br = n0 + g*8 + lrow;
      load_lds16(Bb + br*(long)K + (k0 + gchunk*8), &Bs[g*512]);
    }
    __syncthreads();
#pragma unroll
    for (int ks=0;ks<2;ks++){
      bf16x8 af[4], bfv[4];
      const int qd = (lane>>4) + ks*4;
#pragma unroll
      for (int i=0;i<4;i++){
        const int rowa = wm*64 + i*16 + (lane&15);
        af[i]  = *(const bf16x8*)&As[rowa*64 + ((qd ^ (rowa&7))<<3)];
        const int rowb = wn*64 + i*16 + (lane&15);
        bfv[i] = *(const bf16x8*)&Bs[rowb*64 + ((qd ^ (rowb&7))<<3)];
      }
#pragma unroll
      for (int i=0;i<4;i++)
#pragma unroll
        for (int j=0;j<4;j++)
          acc[i][j] = __builtin_amdgcn_mfma_f32_16x16x32_bf16(af[i], bfv[j], acc[i][j], 0, 0, 0);
    }
  }

  // ---------------- epilogue ----------------
  __bf16* st = (__bf16*)smem_raw;      // 128 x 136 bf16
  float*  stf = (float*)smem_raw;      // 128 x 68 f32
  const int quad = lane >> 4;
  const int row = tid >> 1, half = tid & 1;
  const long row_g = m0 + row;

  if (MODE == 4){
#pragma unroll
    for (int p=0;p<2;p++){
      __syncthreads();
      if (wn == p){
#pragma unroll
        for (int i=0;i<4;i++){
          const int tr0 = wm*64 + i*16 + quad*4;
#pragma unroll
          for (int j=0;j<4;j++){
            const int tc = j*16 + (lane&15);
            const float bb = bias[n0 + p*64 + tc];
#pragma unroll
            for (int r=0;r<4;r++) stf[(tr0+r)*68 + tc] = acc[i][j][r] + bb;
          }
        }
      }
      __syncthreads();
#pragma unroll
      for (int k=0;k<8;k++){
        f32x4 c4 = *(const f32x4*)&stf[row*68 + half*32 + k*4];
        const long cg = n0 + p*64 + half*32 + k*4;
        const long idx = row_g*DM + cg;
        bf16x4 h4 = *(const bf16x4*)((const __bf16*)x0 + idx);
        bf16x4 u4 = *(const bf16x4*)((const __bf16*)x1 + idx);
        float4 xv = *(const float4*)((const float*)x2 + idx);
        float4 o;
        o.x = xv.x + (float)u4[0]*(silu_((float)h4[0]+c4[0]) - xv.x);
        o.y = xv.y + (float)u4[1]*(silu_((float)h4[1]+c4[1]) - xv.y);
        o.z = xv.z + (float)u4[2]*(silu_((float)h4[2]+c4[2]) - xv.z);
        o.w = xv.w + (float)u4[3]*(silu_((float)h4[3]+c4[3]) - xv.w);
        *(float4*)((float*)o0 + idx) = o;
      }
    }
    return;
  }

  if (MODE == 5){
    // z-strip (128 cols): produce qx and kx with rotary-affine epilogue
    const float* qkg = (const float*)x0;
    const float* qkb = (const float*)x1;
    __bf16* qx = (__bf16*)o3;
    __bf16* kx = (__bf16*)x2;
#pragma unroll
    for (int pass=0; pass<2; pass++){
      __syncthreads();
#pragma unroll
      for (int i=0;i<4;i++){
        const int tr0 = wm*64 + i*16 + quad*4;
#pragma unroll
        for (int j=0;j<4;j++){
          const int tc = wn*64 + j*16 + (lane&15);
          const float bb = bias[DM + tc];
          const float g = pass ? qkg[ZD+tc] : qkg[tc];
          const float be = pass ? qkb[ZD+tc] : qkb[tc];
          const float sc = pass ? 1.0f : (1.0f/LSEQ);
#pragma unroll
          for (int r=0;r<4;r++){
            const float s = silu_(acc[i][j][r] + bb);
            st[(tr0+r)*136 + tc] = (__bf16)((s*g + be)*sc);
          }
        }
      }
      __syncthreads();
      __bf16* dst = pass ? kx : qx;
      const long ll = row_g >> 2, b = row_g & 3;
      const long base = (b*LSEQ + ll)*NEXTD;
#pragma unroll
      for (int k=0;k<8;k++){
        bf16x8 vv = *(const bf16x8*)&st[row*136 + half*64 + k*8];
        *(bf16x8*)(dst + base + half*64 + k*8) = vv;
      }
    }
    return;
  }

  // staging with per-mode transform
  __syncthreads();
#pragma unroll
  for (int i=0;i<4;i++){
    const int tr0 = wm*64 + i*16 + quad*4;
#pragma unroll
    for (int j=0;j<4;j++){
      const int tc = wn*64 + j*16 + (lane&15);
      const long col = n0 + tc;
      float bb = 0.0f;
      if (MODE==0 || MODE==1) bb = bias[col];
#pragma unroll
      for (int r=0;r<4;r++){
        float c = acc[i][j][r] + bb;
        if (MODE==0) c = silu_(c);
        else if (MODE==1){ c = (col < DM) ? sigm(c) : ((col < DM+ZD+HD) ? silu_(c) : c); }
        else if (MODE==2) c = laplacef(c)*16.0f;   // fp8 scale
        st[(tr0+r)*136 + tc] = (__bf16)c;
      }
    }
  }
  __syncthreads();

  if (MODE==2){
    // fp8 store: S8[b][l][m], value = laplace*16
    uchar* dst = (uchar*)o0;
    const long base = (long)bz*LSEQ*LSEQ + row_g*LSEQ + n0 + half*64;
#pragma unroll
    for (int k=0;k<4;k++){
      bf16x8 v0 = *(const bf16x8*)&st[row*136 + half*64 + k*16];
      bf16x8 v1 = *(const bf16x8*)&st[row*136 + half*64 + k*16 + 8];
      uint4 ov;
      ov.x = pk4_fp8((float)v0[0],(float)v0[1],(float)v0[2],(float)v0[3]);
      ov.y = pk4_fp8((float)v0[4],(float)v0[5],(float)v0[6],(float)v0[7]);
      ov.z = pk4_fp8((float)v1[0],(float)v1[1],(float)v1[2],(float)v1[3]);
      ov.w = pk4_fp8((float)v1[4],(float)v1[5],(float)v1[6],(float)v1[7]);
      *(uint4*)(dst + base + k*16) = ov;
    }
  } else {
    __bf16* dst; long ld, coff;
    if (MODE==0){ dst = (__bf16*)o0; ld = HD; coff = n0; }
    else {
      if (n0 < DM)            { dst = (__bf16*)o0; ld = DM; coff = n0; }          // u
      else if (n0 < DM+ZD+HD) { dst = (__bf16*)o1; ld = HD; coff = n0-DM-ZD; }    // r
      else                    { dst = (__bf16*)o2; ld = DM; coff = n0-DM-ZD-HD; } // hx
    }
    const long base = row_g*ld + coff + half*64;
#pragma unroll
    for (int k=0;k<8;k++){
      bf16x8 vv = *(const bf16x8*)&st[row*136 + half*64 + k*8];
      *(bf16x8*)(dst + base + k*8) = vv;
    }
  }
}

// ---------------- fp8 GEMM: a3 = (S8 @ vT8^T)/128 * r ----------------
__global__ __launch_bounds__(256, 4) void gemm_fp8_att(
    const uchar* __restrict__ S8, const uchar* __restrict__ V8,
    const __bf16* __restrict__ rgate, __bf16* __restrict__ a3)
{
  __shared__ __align__(16) char smem_raw[34816];
  uchar* As = (uchar*)smem_raw;
  uchar* Bs = (uchar*)smem_raw + 8192;
  const int tid = threadIdx.x;
  const int lane = tid & 63;
  const int wid = tid >> 6;
  const int bz = blockIdx.z;
  long m0, n0;
  xcd_supertile(m0, n0, 128);
  const uchar* Ab = S8 + (long)bz * LSEQ * LSEQ;
  const uchar* Bb = V8 + (long)bz * (long)HD * LSEQ;
  const int wm = wid & 1, wn = wid >> 1;
  const int srow = lane >> 2;
  const int schunk = lane & 3;

  f32x4 acc[4][4];
#pragma unroll
  for (int i=0;i<4;i++)
#pragma unroll
    for (int j=0;j<4;j++)
#pragma unroll
      for (int r=0;r<4;r++) acc[i][j][r] = 0.0f;

  for (int k0=0;k0<LSEQ;k0+=64){
    __syncthreads();
#pragma unroll
    for (int j=0;j<2;j++){
      const int g = j*4 + wid;
      const int rr = g*16 + srow;
      const int gc = schunk ^ ((rr>>1)&3);
      load_lds16b(Ab + (m0+rr)*(long)LSEQ + k0 + gc*16, &As[g*1024]);
      load_lds16b(Bb + (n0+rr)*(long)LSEQ + k0 + gc*16, &Bs[g*1024]);
    }
    __syncthreads();
#pragma unroll
    for (int mi=0;mi<2;mi++){
      const int g = mi*4 + (lane>>4);
      long af[4], bfr[4];
#pragma unroll
      for (int i=0;i<4;i++){
        const int ra = wm*64 + i*16 + (lane&15);
        af[i]  = *(const long*)&As[ra*64 + ((g ^ (ra&6))<<3)];
        const int rb = wn*64 + i*16 + (lane&15);
        bfr[i] = *(const long*)&Bs[rb*64 + ((g ^ (rb&6))<<3)];
      }
#pragma unroll
      for (int i=0;i<4;i++)
#pragma unroll
        for (int j=0;j<4;j++)
          acc[i][j] = __builtin_amdgcn_mfma_f32_16x16x32_fp8_fp8(af[i], bfr[j], acc[i][j], 0, 0, 0);
    }
  }

  __bf16* st = (__bf16*)smem_raw;
  const int quad = lane >> 4;
  const int row = tid >> 1, half = tid & 1;
  const long row_g = m0 + row;
  __syncthreads();
#pragma unroll
  for (int i=0;i<4;i++){
    const int tr0 = wm*64 + i*16 + quad*4;
#pragma unroll
    for (int j=0;j<4;j++){
      const int tc = wn*64 + j*16 + (lane&15);
#pragma unroll
      for (int r=0;r<4;r++)
        st[(tr0+r)*136 + tc] = (__bf16)(acc[i][j][r] * (1.0f/128.0f));
    }
  }
  __syncthreads();
  const long base = (row_g*NB + bz)*HD + n0 + half*64;
#pragma unroll
  for (int k=0;k<8;k++){
    bf16x8 vv = *(const bf16x8*)&st[row*136 + half*64 + k*8];
    bf16x8 rv = *(const bf16x8*)(rgate + base + k*8);
    bf16x8 ov;
#pragma unroll
    for (int e=0;e<8;e++) ov[e] = (__bf16)((float)vv[e]*(float)rv[e]);
    *(bf16x8*)(a3 + base + k*8) = ov;
  }
}

extern "C" void kernel_launch(void* const* d_in, const int* in_sizes, int n_in,
                              void* d_out, int out_size, void* d_ws, size_t ws_size,
                              hipStream_t stream) {
  const float* x      = (const float*)d_in[0];
  const float* edelta = (const float*)d_in[1];
  const float* ealpha = (const float*)d_in[2];
  const float* ebeta  = (const float*)d_in[3];
  const float* egamma = (const float*)d_in[4];
  const float* eomega = (const float*)d_in[5];
  const float* lnw    = (const float*)d_in[6];
  const float* lnb    = (const float*)d_in[7];
  const float* Wv     = (const float*)d_in[8];
  const float* bv     = (const float*)d_in[9];
  const float* Wmx    = (const float*)d_in[10];
  const float* bmx    = (const float*)d_in[11];
  const float* Wh     = (const float*)d_in[12];
  const float* bh     = (const float*)d_in[13];
  const float* qkg    = (const float*)d_in[14];
  const float* qkb    = (const float*)d_in[15];
  const float* ralpha = (const float*)d_in[16];
  const float* rbeta  = (const float*)d_in[17];
  float* out = (float*)d_out;

  char* ws = (char*)d_ws;
  size_t off = 0;
  auto alloc = [&](size_t bytes) -> char* {
    char* p = ws + off; off = (off + bytes + 255) & ~(size_t)255; return p;
  };
  char* p_S8   = alloc(16777216);  // S fp8 [b][l][m] (laplace*16)
  char* p_xnb  = alloc(16777216);  // xn bf16 [l][b][d]
  char* p_qx   = alloc(4194304);   // qx bf16 [b][l][256]
  char* p_kx   = alloc(4194304);   // kx bf16 [b][l][256]
  char* p_mx   = alloc(16777216);  // mx bf16 [l][b][d]
  char* p_wvb  = alloc(4194304);
  char* p_wmxb = alloc(8650752);   // permuted: [u | r | hx | z]
  char* p_whb  = alloc(4194304);
  char* p_eq   = alloc(65536);
  char* p_ew   = alloc(65536);
  char* p_qc   = alloc(65536);
  char* p_v    = alloc(33554432);  // v bf16 [l][b][h]; later aliased by a3
  char* p_vT8  = alloc(16777216);  // vT fp8 [b][h][l] (v*8)
  char* p_u    = alloc(16777216);  // u bf16 ; EMA aliases: E(8MB)+Sinit(8MB)
  char* p_r    = alloc(33554432);  // r bf16 [l][b][h]
  char* p_hx   = alloc(16777216);  // hx bf16

  float* p_E  = (float*)p_u;
  float* p_si = (float*)(p_u + 8388608);

  f2b_all<<<8320, 256, 0, stream>>>((const float4*)Wv, (const float4*)Wmx, (const float4*)Wh,
                                    (bf16x4*)p_wvb, (bf16x4*)p_wmxb, (bf16x4*)p_whb);
  ema_params_k<<<64, 256, 0, stream>>>(edelta, ealpha, ebeta, egamma,
                                       (float*)p_eq, (float*)p_ew, (float*)p_qc);
  ln_kernel<<<8192, 256, 0, stream>>>(x, lnw, lnb, (__bf16*)p_xnb);

  ema_chunk_k<<<dim3(16,EMA_NCH,4), 64, 0, stream>>>((const __bf16*)p_xnb, (const float*)p_eq, p_E);
  ema_scan_k<<<256, 256, 0, stream>>>(p_E, (const float*)p_qc, p_si);
  ema_out_k<<<dim3(16,EMA_NCH,4), 64, 0, stream>>>((const __bf16*)p_xnb, (const float*)p_eq,
                                                   (const float*)p_ew, eomega, p_si, (__bf16*)p_mx);

  // v = silu(xn @ Wv^T + bv)   [256-tile 8-phase, fence-free]
  gemm256<0><<<dim3(32,8,1), 512, 0, stream>>>((const __bf16*)p_xnb, (const __bf16*)p_wvb,
      1024, bv, p_v, nullptr, nullptr);
  transpose_v8<<<dim3(32,32,4), 256, 0, stream>>>((const __bf16*)p_v, (uchar*)p_vT8);

  // base = mx @ Wmx^T + bmx -> u / r / hx  [256-tile 8-phase over permuted 4096 cols]
  gemm256<1><<<dim3(32,16,1), 512, 0, stream>>>((const __bf16*)p_mx, (const __bf16*)p_wmxb,
      1024, bmx, p_u, p_r, p_hx);
  // z-strip (permuted rows [4096,4224)) -> qx,kx  [m97 128-tile path]
  gemm_bt<5><<<dim3(64,1,1), 256, 0, stream>>>((const __bf16*)p_mx,
      (const __bf16*)p_wmxb + (long)4096*1024, 1024, 0, 0, bmx,
      nullptr, nullptr, nullptr, p_qx, qkg, qkb, p_kx);
  rot_fill<<<LSEQ, 128, 0, stream>>>(ralpha, rbeta, (__bf16*)p_qx, (__bf16*)p_kx);

  // S8 = fp8(laplace(qx @ kx^T) * 16)
  gemm_bt<2><<<dim3(16,16,4), 256, 0, stream>>>((const __bf16*)p_qx, (const __bf16*)p_kx,
      256, (long)LSEQ*NEXTD, (long)LSEQ*NEXTD, nullptr, p_S8, nullptr, nullptr, nullptr,
      nullptr, nullptr, nullptr);

  // a3 = (S8 @ vT8^T)/128 * r
  __bf16* a3 = (__bf16*)p_v;
  gemm_fp8_att<<<dim3(16,16,4), 256, 0, stream>>>((const uchar*)p_S8, (const uchar*)p_vT8,
      (const __bf16*)p_r, a3);

  // out = x + u*(silu(hx + a3 @ Wh^T + bh) - x)
  gemm_bt<4><<<dim3(64,8,1), 256, 0, stream>>>(a3, (const __bf16*)p_whb,
      2048, 0, 0, bh, out, nullptr, nullptr, nullptr, p_hx, p_u, x);
}

// Round 4
// 476.252 us; speedup vs baseline: 1.3197x; 1.3197x over previous
//
#include <hip/hip_runtime.h>
#include <hip/hip_bf16.h>
#include <math.h>

#define LSEQ 2048
#define NB 4
#define DM 1024
#define ZD 128
#define HD 2048
#define ND 16
#define NEXTD 256
#define EMA_C 64
#define EMA_NCH 32

typedef __bf16 bf16x8 __attribute__((ext_vector_type(8)));
typedef __bf16 bf16x4 __attribute__((ext_vector_type(4)));
typedef float f32x4 __attribute__((ext_vector_type(4)));
typedef unsigned char uchar;

__device__ __forceinline__ float sigm(float x){ return 1.0f/(1.0f+expf(-x)); }
__device__ __forceinline__ float silu_(float x){ return x/(1.0f+expf(-x)); }
__device__ __forceinline__ float laplacef(float x){ return 0.5f*(1.0f+erff((x-0.70710678f)*2.5066282746f)); }

__device__ __forceinline__ void load_lds16(const __bf16* g, __bf16* l){
  __builtin_amdgcn_global_load_lds((const __attribute__((address_space(1))) void*)g,
                                   (__attribute__((address_space(3))) void*)l, 16, 0, 0);
}
__device__ __forceinline__ void load_lds16b(const uchar* g, uchar* l){
  __builtin_amdgcn_global_load_lds((const __attribute__((address_space(1))) void*)g,
                                   (__attribute__((address_space(3))) void*)l, 16, 0, 0);
}
// pack 4 f32 -> 4 fp8 e4m3 bytes (OCP on gfx950)
__device__ __forceinline__ unsigned int pk4_fp8(float a, float b, float c, float d){
  int v = __builtin_amdgcn_cvt_pk_fp8_f32(a, b, 0, false);
  v = __builtin_amdgcn_cvt_pk_fp8_f32(c, d, v, true);
  return (unsigned int)v;
}

// ---------------- weights fp32 -> bf16 (3 mats) + EMA params, one launch ----------------
__global__ __launch_bounds__(256) void f2b_ema(const float4* __restrict__ w0, const float4* __restrict__ w1,
                                               const float4* __restrict__ w2, bf16x4* __restrict__ o0,
                                               bf16x4* __restrict__ o1, bf16x4* __restrict__ o2,
                                               const float* __restrict__ de, const float* __restrict__ al,
                                               const float* __restrict__ be, const float* __restrict__ ga,
                                               float* __restrict__ qo, float* __restrict__ wo,
                                               float* __restrict__ qco){
  const int bid = blockIdx.x;
  if (bid >= 8320){
    const int i = (bid-8320)*256 + threadIdx.x;
    const float p = sigm(de[i]);
    const float q = 1.0f - p*sigm(al[i]);
    qo[i] = q;
    wo[i] = p*be[i]*ga[i]*0.25f;
    qco[i] = powf(q, (float)EMA_C);
    return;
  }
  const int i = bid*256 + threadIdx.x;
  const int n0 = 524288, n1 = 1081344, n2 = 524288;
  const float4* src; bf16x4* dst; int k;
  if (i < n0){ src = w0; dst = o0; k = i; }
  else if (i < n0+n1){ src = w1; dst = o1; k = i-n0; }
  else if (i < n0+n1+n2){ src = w2; dst = o2; k = i-n0-n1; }
  else return;
  float4 v = src[k];
  bf16x4 o; o[0]=(__bf16)v.x; o[1]=(__bf16)v.y; o[2]=(__bf16)v.z; o[3]=(__bf16)v.w;
  dst[k] = o;
}

// ---------------- LayerNorm (bf16 out, l-major [l][b][d]) ----------------
__global__ __launch_bounds__(256) void ln_kernel(const float* __restrict__ x, const float* __restrict__ w,
                                                 const float* __restrict__ b, __bf16* __restrict__ xnb){
  const long row = blockIdx.x;
  const int tid = threadIdx.x;
  float4 v = ((const float4*)(x + row*DM))[tid];
  float s = v.x+v.y+v.z+v.w;
  float ss = v.x*v.x+v.y*v.y+v.z*v.z+v.w*v.w;
#pragma unroll
  for (int o=32;o>0;o>>=1){ s += __shfl_down(s,o); ss += __shfl_down(ss,o); }
  __shared__ float red[8];
  __shared__ float mv[2];
  const int wid2 = tid>>6, lane = tid&63;
  if (lane==0){ red[wid2]=s; red[4+wid2]=ss; }
  __syncthreads();
  if (tid==0){
    float ts = red[0]+red[1]+red[2]+red[3];
    float tss = red[4]+red[5]+red[6]+red[7];
    float mean = ts*(1.0f/DM);
    float var = tss*(1.0f/DM) - mean*mean;
    mv[0]=mean; mv[1]=rsqrtf(var + 1e-5f);
  }
  __syncthreads();
  const float mean=mv[0], rs=mv[1];
  float4 wv = ((const float4*)w)[tid];
  float4 bv = ((const float4*)b)[tid];
  bf16x4 ob;
  ob[0]=(__bf16)((v.x-mean)*rs*wv.x+bv.x);
  ob[1]=(__bf16)((v.y-mean)*rs*wv.y+bv.y);
  ob[2]=(__bf16)((v.z-mean)*rs*wv.z+bv.z);
  ob[3]=(__bf16)((v.w-mean)*rs*wv.w+bv.w);
  ((bf16x4*)(xnb + row*DM))[tid]=ob;
}

// ---------------- EMA pass A ----------------
__global__ __launch_bounds__(64) void ema_chunk_k(const __bf16* __restrict__ xn, const float* __restrict__ qp,
                                                  float* __restrict__ E){
  const int d = blockIdx.x*64 + threadIdx.x;
  const int j = blockIdx.y, b = blockIdx.z;
  float q[ND], s[ND];
#pragma unroll
  for (int n=0;n<ND;n++){ q[n]=qp[d*ND+n]; s[n]=0.0f; }
  const __bf16* xc = xn + (long)b*DM + d + (long)j*EMA_C*(NB*DM);
#pragma unroll
  for (int lt=0; lt<EMA_C; lt+=4){
    float xv[4];
#pragma unroll
    for (int u=0;u<4;u++) xv[u] = (float)xc[(long)(lt+u)*(NB*DM)];
#pragma unroll
    for (int u=0;u<4;u++)
#pragma unroll
      for (int n=0;n<ND;n++) s[n] = fmaf(q[n], s[n], xv[u]);
  }
  float4* Eo = (float4*)(E + (((long)b*EMA_NCH + j)*DM + d)*ND);
#pragma unroll
  for (int n=0;n<4;n++) Eo[n] = make_float4(s[4*n], s[4*n+1], s[4*n+2], s[4*n+3]);
}

// ---------------- EMA pass B ----------------
__global__ __launch_bounds__(256) void ema_scan_k(const float* __restrict__ E, const float* __restrict__ qc,
                                                  float* __restrict__ Sinit){
  const int t = blockIdx.x*256 + threadIdx.x;
  const int b = t >> 14;
  const int rem = t & 16383;
  const float q64 = qc[rem];
  float s = 0.0f;
  const long base = (long)b*EMA_NCH*16384 + rem;
  for (int j=0;j<EMA_NCH;j++){
    const long idx = base + (long)j*16384;
    Sinit[idx] = s;
    s = fmaf(q64, s, E[idx]);
  }
}

// ---------------- EMA pass C ----------------
__global__ __launch_bounds__(64) void ema_out_k(const __bf16* __restrict__ xn, const float* __restrict__ qp,
                                                const float* __restrict__ wp, const float* __restrict__ omega,
                                                const float* __restrict__ Sinit, __bf16* __restrict__ mx){
  const int d = blockIdx.x*64 + threadIdx.x;
  const int j = blockIdx.y, b = blockIdx.z;
  float q[ND], w[ND], s[ND];
  const float4* Si = (const float4*)(Sinit + (((long)b*EMA_NCH + j)*DM + d)*ND);
#pragma unroll
  for (int n=0;n<4;n++){ float4 v=Si[n]; s[4*n]=v.x; s[4*n+1]=v.y; s[4*n+2]=v.z; s[4*n+3]=v.w; }
#pragma unroll
  for (int n=0;n<ND;n++){ q[n]=qp[d*ND+n]; w[n]=wp[d*ND+n]; }
  const float om = omega[d];
  const int l0 = j*EMA_C;
  const __bf16* xc = xn + (long)b*DM + d;
#pragma unroll
  for (int lt=0; lt<EMA_C; lt+=4){
    float xv[4];
#pragma unroll
    for (int u=0;u<4;u++) xv[u] = (float)xc[(long)(l0+lt+u)*(NB*DM)];
#pragma unroll
    for (int u=0;u<4;u++){
      float a = 0.0f;
#pragma unroll
      for (int n=0;n<ND;n++){ s[n] = fmaf(q[n], s[n], xv[u]); a = fmaf(w[n], s[n], a); }
      mx[((long)(l0+lt+u)*NB + b)*DM + d] = (__bf16)silu_(a + xv[u]*om);
    }
  }
}

// Supertiled XCD remap: XCD k owns m-tiles [k*mpx,(k+1)*mpx) x all n-tiles,
// so per-XCD A-working-set stays L2-resident. gridDim.x must be 8*pow2.
__device__ __forceinline__ void xcd_supertile(long& m0, long& n0, int tileDim){
  const int orig = blockIdx.y*gridDim.x + blockIdx.x;
  const int xcd = orig & 7, j = orig >> 3;
  const int mpx = gridDim.x >> 3;            // power of 2 in all launches
  const int sh = __builtin_ctz(mpx);
  m0 = (long)((xcd<<sh) + (j & (mpx-1))) * tileDim;
  n0 = (long)(j >> sh) * tileDim;
}

// ---------------- bf16 GEMM template (16x16x32 MFMA, m97 structure) ----------------
// __launch_bounds__(256,4): 4 blocks/CU residency (TLP hides staging latency).
// MODE: 0 = v-GEMM, epilogue writes vT8 fp8 [b][h][l] (x8 scale) DIRECTLY (no bf16 v)
//       1 = base split: u(sigm)/qk(n0==DM, incl. fused rotary ext)/r(silu)/hx(id)
//       2 = laplace*16 -> fp8 S      4 = final fused f32 out
template<int MODE>
__global__ __launch_bounds__(256, 4) void gemm_bt(
    const __bf16* __restrict__ A, const __bf16* __restrict__ Bw,
    int K, long aBatch, long bBatch, const float* __restrict__ bias,
    void* __restrict__ o0, void* __restrict__ o1, void* __restrict__ o2, void* __restrict__ o3,
    const void* __restrict__ x0, const void* __restrict__ x1, const void* __restrict__ x2,
    const void* __restrict__ x3, const void* __restrict__ x4)
{
  __shared__ __align__(16) char smem_raw[34816];
  __bf16* As = (__bf16*)smem_raw;
  __bf16* Bs = (__bf16*)(smem_raw + 16384);
  const int tid = threadIdx.x;
  const int lane = tid & 63;
  const int wid = tid >> 6;
  const int bz = blockIdx.z;
  long m0, n0;
  xcd_supertile(m0, n0, 128);
  const __bf16* Ab = A + (long)bz * aBatch;
  const __bf16* Bb = Bw + (long)bz * bBatch;
  const int wm = wid & 1, wn = wid >> 1;
  const int lrow = lane >> 3;
  const int gchunk = (lane & 7) ^ lrow;

  f32x4 acc[4][4];
#pragma unroll
  for (int i=0;i<4;i++)
#pragma unroll
    for (int j=0;j<4;j++)
#pragma unroll
      for (int r=0;r<4;r++) acc[i][j][r] = 0.0f;

  for (int k0=0;k0<K;k0+=64){
    __syncthreads();
#pragma unroll
    for (int j=0;j<4;j++){
      const int g = j*4 + wid;
      const long ar = m0 + g*8 + lrow;
      load_lds16(Ab + ar*(long)K + (k0 + gchunk*8), &As[g*512]);
      const long br = n0 + g*8 + lrow;
      load_lds16(Bb + br*(long)K + (k0 + gchunk*8), &Bs[g*512]);
    }
    __syncthreads();
#pragma unroll
    for (int ks=0;ks<2;ks++){
      bf16x8 af[4], bfv[4];
      const int qd = (lane>>4) + ks*4;
#pragma unroll
      for (int i=0;i<4;i++){
        const int rowa = wm*64 + i*16 + (lane&15);
        af[i]  = *(const bf16x8*)&As[rowa*64 + ((qd ^ (rowa&7))<<3)];
        const int rowb = wn*64 + i*16 + (lane&15);
        bfv[i] = *(const bf16x8*)&Bs[rowb*64 + ((qd ^ (rowb&7))<<3)];
      }
#pragma unroll
      for (int i=0;i<4;i++)
#pragma unroll
        for (int j=0;j<4;j++)
          acc[i][j] = __builtin_amdgcn_mfma_f32_16x16x32_bf16(af[i], bfv[j], acc[i][j], 0, 0, 0);
    }
  }

  // ---------------- epilogue ----------------
  __bf16* st = (__bf16*)smem_raw;      // 128 x 136 bf16
  float*  stf = (float*)smem_raw;      // 128 x 68 f32
  const int quad = lane >> 4;
  const int row = tid >> 1, half = tid & 1;
  const long row_g = m0 + row;

  if (MODE == 4){
#pragma unroll
    for (int p=0;p<2;p++){
      __syncthreads();
      if (wn == p){
#pragma unroll
        for (int i=0;i<4;i++){
          const int tr0 = wm*64 + i*16 + quad*4;
#pragma unroll
          for (int j=0;j<4;j++){
            const int tc = j*16 + (lane&15);
            const float bb = bias[n0 + p*64 + tc];
#pragma unroll
            for (int r=0;r<4;r++) stf[(tr0+r)*68 + tc] = acc[i][j][r] + bb;
          }
        }
      }
      __syncthreads();
#pragma unroll
      for (int k=0;k<8;k++){
        f32x4 c4 = *(const f32x4*)&stf[row*68 + half*32 + k*4];
        const long cg = n0 + p*64 + half*32 + k*4;
        const long idx = row_g*DM + cg;
        bf16x4 h4 = *(const bf16x4*)((const __bf16*)x0 + idx);
        bf16x4 u4 = *(const bf16x4*)((const __bf16*)x1 + idx);
        float4 xv = *(const float4*)((const float*)x2 + idx);
        float4 o;
        o.x = xv.x + (float)u4[0]*(silu_((float)h4[0]+c4[0]) - xv.x);
        o.y = xv.y + (float)u4[1]*(silu_((float)h4[1]+c4[1]) - xv.y);
        o.z = xv.z + (float)u4[2]*(silu_((float)h4[2]+c4[2]) - xv.z);
        o.w = xv.w + (float)u4[3]*(silu_((float)h4[3]+c4[3]) - xv.w);
        *(float4*)((float*)o0 + idx) = o;
      }
    }
    return;
  }

  if (MODE == 1 && n0 == DM){
    // z-strip: qx/kx cols [0,128) via GEMM epilogue + fused rotary cols [128,256)
    const float* qkg = (const float*)x0;
    const float* qkb = (const float*)x1;
    __bf16* qx = (__bf16*)o3;
    __bf16* kx = (__bf16*)x2;
#pragma unroll
    for (int pass=0; pass<2; pass++){
      __syncthreads();
#pragma unroll
      for (int i=0;i<4;i++){
        const int tr0 = wm*64 + i*16 + quad*4;
#pragma unroll
        for (int j=0;j<4;j++){
          const int tc = wn*64 + j*16 + (lane&15);
          const float bb = bias[DM + tc];
          const float g = pass ? qkg[ZD+tc] : qkg[tc];
          const float be = pass ? qkb[ZD+tc] : qkb[tc];
          const float sc = pass ? 1.0f : (1.0f/LSEQ);
#pragma unroll
          for (int r=0;r<4;r++){
            const float s = silu_(acc[i][j][r] + bb);
            st[(tr0+r)*136 + tc] = (__bf16)((s*g + be)*sc);
          }
        }
      }
      __syncthreads();
      __bf16* dst = pass ? kx : qx;
      const long ll = row_g >> 2, b = row_g & 3;
      const long base = (b*LSEQ + ll)*NEXTD;
#pragma unroll
      for (int k=0;k<8;k++){
        bf16x8 vv = *(const bf16x8*)&st[row*136 + half*64 + k*8];
        *(bf16x8*)(dst + base + half*64 + k*8) = vv;
      }
    }
    // fused rotary extension for this tile's 32 l values (replaces rot_fill)
    {
      const float* ra = (const float*)x3;
      const float* rb = (const float*)x4;
      const long l0 = m0 >> 2;
      const int i = tid & 127;
      const int lsub = tid >> 7;          // 0/1 -> 16 l each
      const int jf = i & 63;
      const float fr = expf((float)jf * (-0.14391156831f));
      const float sgn = (i < 64) ? -1.0f : 1.0f;
      const float ra0 = ra[i], ra2 = (i<64) ? ra[i+64] : ra[i-64];
      const float rb0 = rb[i], rb2 = (i<64) ? rb[i+64] : rb[i-64];
      for (int t=0; t<16; t++){
        const long l = l0 + lsub*16 + t;
        const float ang = (float)l * fr;
        const float sn = sinf(ang), cs = cosf(ang);
        const __bf16 qb = (__bf16)(ra0*cs + sgn*ra2*sn);
        const __bf16 kb = (__bf16)(rb0*cs + sgn*rb2*sn);
#pragma unroll
        for (int b=0;b<4;b++){
          const long o = ((long)b*LSEQ + l)*NEXTD + 128 + i;
          qx[o] = qb;
          kx[o] = kb;
        }
      }
    }
    return;
  }

  // staging with per-mode transform
  __syncthreads();
#pragma unroll
  for (int i=0;i<4;i++){
    const int tr0 = wm*64 + i*16 + quad*4;
#pragma unroll
    for (int j=0;j<4;j++){
      const int tc = wn*64 + j*16 + (lane&15);
      const long col = n0 + tc;
      float bb = 0.0f;
      if (MODE==0 || MODE==1) bb = bias[col];
#pragma unroll
      for (int r=0;r<4;r++){
        float c = acc[i][j][r] + bb;
        if (MODE==0) c = silu_(c);
        else if (MODE==1){ c = (col < DM) ? sigm(c) : ((col < DM+ZD+HD) ? silu_(c) : c); }
        else if (MODE==2) c = laplacef(c)*16.0f;   // fp8 scale
        st[(tr0+r)*136 + tc] = (__bf16)c;
      }
    }
  }
  __syncthreads();

  if (MODE==0){
    // direct transposed fp8 store: vT8[b][h][l] = fp8(8*silu(...)), replaces
    // the bf16 v buffer + transpose_v8 kernel entirely.
    uchar* vT = (uchar*)o0;
    const long l0v = m0 >> 2;            // 32 l values per tile
    const int hl = tid & 127;            // tile-local h
    const int b0 = tid >> 7;             // 0/1
#pragma unroll
    for (int bb=0; bb<2; bb++){
      const int b = b0 + 2*bb;
      unsigned int pk[8];
#pragma unroll
      for (int k=0;k<8;k++){
        float a0 = 8.0f*(float)st[((k*4+0)*4+b)*136 + hl];
        float a1 = 8.0f*(float)st[((k*4+1)*4+b)*136 + hl];
        float a2 = 8.0f*(float)st[((k*4+2)*4+b)*136 + hl];
        float a3 = 8.0f*(float)st[((k*4+3)*4+b)*136 + hl];
        pk[k] = pk4_fp8(a0,a1,a2,a3);
      }
      uchar* dst = vT + ((long)b*HD + n0 + hl)*LSEQ + l0v;
      *(uint4*)dst      = make_uint4(pk[0],pk[1],pk[2],pk[3]);
      *(uint4*)(dst+16) = make_uint4(pk[4],pk[5],pk[6],pk[7]);
    }
  } else if (MODE==2){
    // fp8 store: S8[b][l][m], value = laplace*16
    uchar* dst = (uchar*)o0;
    const long base = (long)bz*LSEQ*LSEQ + row_g*LSEQ + n0 + half*64;
#pragma unroll
    for (int k=0;k<4;k++){
      bf16x8 v0 = *(const bf16x8*)&st[row*136 + half*64 + k*16];
      bf16x8 v1 = *(const bf16x8*)&st[row*136 + half*64 + k*16 + 8];
      uint4 ov;
      ov.x = pk4_fp8((float)v0[0],(float)v0[1],(float)v0[2],(float)v0[3]);
      ov.y = pk4_fp8((float)v0[4],(float)v0[5],(float)v0[6],(float)v0[7]);
      ov.z = pk4_fp8((float)v1[0],(float)v1[1],(float)v1[2],(float)v1[3]);
      ov.w = pk4_fp8((float)v1[4],(float)v1[5],(float)v1[6],(float)v1[7]);
      *(uint4*)(dst + base + k*16) = ov;
    }
  } else {
    __bf16* dst; long ld, coff;
    if (n0 < DM)            { dst = (__bf16*)o0; ld = DM; coff = n0; }          // u
    else if (n0 < DM+ZD+HD) { dst = (__bf16*)o1; ld = HD; coff = n0-DM-ZD; }    // r
    else                    { dst = (__bf16*)o2; ld = DM; coff = n0-DM-ZD-HD; } // hx
    const long base = row_g*ld + coff + half*64;
#pragma unroll
    for (int k=0;k<8;k++){
      bf16x8 vv = *(const bf16x8*)&st[row*136 + half*64 + k*8];
      *(bf16x8*)(dst + base + k*8) = vv;
    }
  }
}

// ---------------- fp8 GEMM: a3 = (S8 @ vT8^T)/128 * r ----------------
__global__ __launch_bounds__(256, 4) void gemm_fp8_att(
    const uchar* __restrict__ S8, const uchar* __restrict__ V8,
    const __bf16* __restrict__ rgate, __bf16* __restrict__ a3)
{
  __shared__ __align__(16) char smem_raw[34816];
  uchar* As = (uchar*)smem_raw;
  uchar* Bs = (uchar*)smem_raw + 8192;
  const int tid = threadIdx.x;
  const int lane = tid & 63;
  const int wid = tid >> 6;
  const int bz = blockIdx.z;
  long m0, n0;
  xcd_supertile(m0, n0, 128);
  const uchar* Ab = S8 + (long)bz * LSEQ * LSEQ;
  const uchar* Bb = V8 + (long)bz * (long)HD * LSEQ;
  const int wm = wid & 1, wn = wid >> 1;
  const int srow = lane >> 2;
  const int schunk = lane & 3;

  f32x4 acc[4][4];
#pragma unroll
  for (int i=0;i<4;i++)
#pragma unroll
    for (int j=0;j<4;j++)
#pragma unroll
      for (int r=0;r<4;r++) acc[i][j][r] = 0.0f;

  for (int k0=0;k0<LSEQ;k0+=64){
    __syncthreads();
#pragma unroll
    for (int j=0;j<2;j++){
      const int g = j*4 + wid;
      const int rr = g*16 + srow;
      const int gc = schunk ^ ((rr>>1)&3);
      load_lds16b(Ab + (m0+rr)*(long)LSEQ + k0 + gc*16, &As[g*1024]);
      load_lds16b(Bb + (n0+rr)*(long)LSEQ + k0 + gc*16, &Bs[g*1024]);
    }
    __syncthreads();
#pragma unroll
    for (int mi=0;mi<2;mi++){
      const int g = mi*4 + (lane>>4);
      long af[4], bfr[4];
#pragma unroll
      for (int i=0;i<4;i++){
        const int ra = wm*64 + i*16 + (lane&15);
        af[i]  = *(const long*)&As[ra*64 + ((g ^ (ra&6))<<3)];
        const int rb = wn*64 + i*16 + (lane&15);
        bfr[i] = *(const long*)&Bs[rb*64 + ((g ^ (rb&6))<<3)];
      }
#pragma unroll
      for (int i=0;i<4;i++)
#pragma unroll
        for (int j=0;j<4;j++)
          acc[i][j] = __builtin_amdgcn_mfma_f32_16x16x32_fp8_fp8(af[i], bfr[j], acc[i][j], 0, 0, 0);
    }
  }

  __bf16* st = (__bf16*)smem_raw;
  const int quad = lane >> 4;
  const int row = tid >> 1, half = tid & 1;
  const long row_g = m0 + row;
  __syncthreads();
#pragma unroll
  for (int i=0;i<4;i++){
    const int tr0 = wm*64 + i*16 + quad*4;
#pragma unroll
    for (int j=0;j<4;j++){
      const int tc = wn*64 + j*16 + (lane&15);
#pragma unroll
      for (int r=0;r<4;r++)
        st[(tr0+r)*136 + tc] = (__bf16)(acc[i][j][r] * (1.0f/128.0f));
    }
  }
  __syncthreads();
  const long base = (row_g*NB + bz)*HD + n0 + half*64;
#pragma unroll
  for (int k=0;k<8;k++){
    bf16x8 vv = *(const bf16x8*)&st[row*136 + half*64 + k*8];
    bf16x8 rv = *(const bf16x8*)(rgate + base + k*8);
    bf16x8 ov;
#pragma unroll
    for (int e=0;e<8;e++) ov[e] = (__bf16)((float)vv[e]*(float)rv[e]);
    *(bf16x8*)(a3 + base + k*8) = ov;
  }
}

extern "C" void kernel_launch(void* const* d_in, const int* in_sizes, int n_in,
                              void* d_out, int out_size, void* d_ws, size_t ws_size,
                              hipStream_t stream) {
  const float* x      = (const float*)d_in[0];
  const float* edelta = (const float*)d_in[1];
  const float* ealpha = (const float*)d_in[2];
  const float* ebeta  = (const float*)d_in[3];
  const float* egamma = (const float*)d_in[4];
  const float* eomega = (const float*)d_in[5];
  const float* lnw    = (const float*)d_in[6];
  const float* lnb    = (const float*)d_in[7];
  const float* Wv     = (const float*)d_in[8];
  const float* bv     = (const float*)d_in[9];
  const float* Wmx    = (const float*)d_in[10];
  const float* bmx    = (const float*)d_in[11];
  const float* Wh     = (const float*)d_in[12];
  const float* bh     = (const float*)d_in[13];
  const float* qkg    = (const float*)d_in[14];
  const float* qkb    = (const float*)d_in[15];
  const float* ralpha = (const float*)d_in[16];
  const float* rbeta  = (const float*)d_in[17];
  float* out = (float*)d_out;

  char* ws = (char*)d_ws;
  size_t off = 0;
  auto alloc = [&](size_t bytes) -> char* {
    char* p = ws + off; off = (off + bytes + 255) & ~(size_t)255; return p;
  };
  char* p_S8   = alloc(16777216);  // S fp8 [b][l][m] (laplace*16)
  char* p_xnb  = alloc(16777216);  // xn bf16 [l][b][d]
  char* p_qx   = alloc(4194304);   // qx bf16 [b][l][256]
  char* p_kx   = alloc(4194304);   // kx bf16 [b][l][256]
  char* p_mx   = alloc(16777216);  // mx bf16 [l][b][d]
  char* p_wvb  = alloc(4194304);
  char* p_wmxb = alloc(8650752);
  char* p_whb  = alloc(4194304);
  char* p_eq   = alloc(65536);
  char* p_ew   = alloc(65536);
  char* p_qc   = alloc(65536);
  char* p_v    = alloc(33554432);  // workspace for a3 bf16 [l][b][h]
  char* p_vT8  = alloc(16777216);  // vT fp8 [b][h][l] (v*8)
  char* p_u    = alloc(16777216);  // u bf16 ; EMA aliases: E(8MB)+Sinit(8MB)
  char* p_r    = alloc(33554432);  // r bf16 [l][b][h]
  char* p_hx   = alloc(16777216);  // hx bf16

  float* p_E  = (float*)p_u;
  float* p_si = (float*)(p_u + 8388608);

  // weights->bf16 + EMA params (fused)
  f2b_ema<<<8384, 256, 0, stream>>>((const float4*)Wv, (const float4*)Wmx, (const float4*)Wh,
                                    (bf16x4*)p_wvb, (bf16x4*)p_wmxb, (bf16x4*)p_whb,
                                    edelta, ealpha, ebeta, egamma,
                                    (float*)p_eq, (float*)p_ew, (float*)p_qc);
  ln_kernel<<<8192, 256, 0, stream>>>(x, lnw, lnb, (__bf16*)p_xnb);

  ema_chunk_k<<<dim3(16,EMA_NCH,4), 64, 0, stream>>>((const __bf16*)p_xnb, (const float*)p_eq, p_E);
  ema_scan_k<<<256, 256, 0, stream>>>(p_E, (const float*)p_qc, p_si);
  ema_out_k<<<dim3(16,EMA_NCH,4), 64, 0, stream>>>((const __bf16*)p_xnb, (const float*)p_eq,
                                                   (const float*)p_ew, eomega, p_si, (__bf16*)p_mx);

  // vT8 = fp8(8 * silu(xn @ Wv^T + bv))^T  [direct transposed store, no bf16 v]
  gemm_bt<0><<<dim3(64,16,1), 256, 0, stream>>>((const __bf16*)p_xnb, (const __bf16*)p_wvb,
      1024, 0, 0, bv, p_vT8, nullptr, nullptr, nullptr, nullptr, nullptr, nullptr,
      nullptr, nullptr);

  // base = mx @ Wmx^T + bmx -> u / (qx,kx incl. rotary) / r / hx
  gemm_bt<1><<<dim3(64,33,1), 256, 0, stream>>>((const __bf16*)p_mx, (const __bf16*)p_wmxb,
      1024, 0, 0, bmx, p_u, p_r, p_hx, p_qx, qkg, qkb, p_kx, ralpha, rbeta);

  // S8 = fp8(laplace(qx @ kx^T) * 16)
  gemm_bt<2><<<dim3(16,16,4), 256, 0, stream>>>((const __bf16*)p_qx, (const __bf16*)p_kx,
      256, (long)LSEQ*NEXTD, (long)LSEQ*NEXTD, nullptr, p_S8, nullptr, nullptr, nullptr,
      nullptr, nullptr, nullptr, nullptr, nullptr);

  // a3 = (S8 @ vT8^T)/128 * r
  __bf16* a3 = (__bf16*)p_v;
  gemm_fp8_att<<<dim3(16,16,4), 256, 0, stream>>>((const uchar*)p_S8, (const uchar*)p_vT8,
      (const __bf16*)p_r, a3);

  // out = x + u*(silu(hx + a3 @ Wh^T + bh) - x)
  gemm_bt<4><<<dim3(64,8,1), 256, 0, stream>>>(a3, (const __bf16*)p_whb,
      2048, 0, 0, bh, out, nullptr, nullptr, nullptr, p_hx, p_u, x,
      nullptr, nullptr);
}